// Round 2
// baseline (4520.979 us; speedup 1.0000x reference)
//
#include <hip/hip_runtime.h>
#include <hip/hip_bf16.h>

// Problem sizes (fixed)
#define BB 32
#define TT 512
#define HH 1024
#define II 1024
#define G4H 4096
#define BH  (BB * HH)          // 32768
#define HD  8                  // h-buffer depth (slots); buffer_inv every HD phases
#define HMASK (HD - 1)

typedef __bf16 bf16x8_t __attribute__((ext_vector_type(8)));
typedef float f32x4_t __attribute__((ext_vector_type(4)));
typedef int i32x4_t __attribute__((ext_vector_type(4)));
typedef unsigned long long u64;

// ---------------------------------------------------------------------------
// Zero slot 0 of both h sequences + arrive counters, via agent-scope
// (write-through) stores so the zeros are durably at the coherence point
// regardless of later buffer_inv. (ws re-poisoned 0xAA each call.)
// ---------------------------------------------------------------------------
__global__ void init_bufs(unsigned* __restrict__ h0w, unsigned* __restrict__ h1w,
                          unsigned* __restrict__ cnt) {
    int i = blockIdx.x * 256 + threadIdx.x;
    if (i < 16384)
        __hip_atomic_store(h0w + i, 0u, __ATOMIC_RELAXED, __HIP_MEMORY_SCOPE_AGENT);
    else if (i < 32768)
        __hip_atomic_store(h1w + (i - 16384), 0u, __ATOMIC_RELAXED, __HIP_MEMORY_SCOPE_AGENT);
    else if (i < 32832)
        __hip_atomic_store(cnt + (i - 32768), 0u, __ATOMIC_RELAXED, __HIP_MEMORY_SCOPE_AGENT);
}

// ---------------------------------------------------------------------------
// Weight shuffle: fp32 [4096][1024] -> bf16 B-fragment order. (unchanged)
// ---------------------------------------------------------------------------
__global__ void shuffle_w(const float* __restrict__ src, __hip_bfloat16* __restrict__ dst) {
    size_t i = (size_t)blockIdx.x * 256 + threadIdx.x;   // 0 .. 4M-1
    int jj   = (int)(i & 7);
    int lane = (int)((i >> 3) & 63);
    int kb   = (int)((i >> 9) & 15);
    int kh   = (int)((i >> 13) & 1);
    int tau  = (int)((i >> 14) & 1);
    int hg   = (int)(i >> 15);
    int n = lane & 15, q = lane >> 4;
    int row = (2 * tau + (n >> 3)) * 1024 + hg * 8 + (n & 7);
    int col = kh * 512 + kb * 32 + q * 8 + jj;
    dst[i] = __float2bfloat16(src[(size_t)row * II + col]);
}

// ---------------------------------------------------------------------------
// x [B][T][I] fp32 -> xb [T][B][I] bf16 (unchanged)
// ---------------------------------------------------------------------------
__global__ void convert_x(const float* __restrict__ x, __hip_bfloat16* __restrict__ xb) {
    size_t i = (size_t)blockIdx.x * 256 + threadIdx.x;   // T*B*I
    int ii = (int)(i & 1023);
    int b  = (int)((i >> 10) & 31);
    int t  = (int)(i >> 15);
    xb[i] = __float2bfloat16(x[((size_t)b * TT + t) * II + ii]);
}

// ---------------------------------------------------------------------------
// Persistent fused 2-layer LSTM. 256 WGs (1/CU) x 512 threads (8 waves).
//
// Design (same as previous round; resubmitted after infra failure, plus a
// bounded poll so any unforeseen protocol hang surfaces as a verification
// failure instead of a dead container):
//  - h state in DEPTH-8 circular buffers h0seq/h1seq[8][BH]; a slot is reused
//    only every 8 phases, so ONE buffer_inv per 8 phases (aligned to the slot
//    cycle) keeps cached h reads stale-free while eliminating mid-GEMM L2
//    wipes. Proof: slot s is read at phases t === s (mod 8); exactly one inv
//    boundary lies in any 8-phase window, after the prior stale read and
//    before the fresh one. Kernel-start inv covers cross-launch staleness.
//  - arrive = ONE agent atomic_add per WG to a per-group counter; ONE thread
//    per WG polls it (was: 128 flag lines x 128 pollers per WG).
//  - h written as 32 x 16B global_store_dwordx4 sc0 sc1 (write-through) by
//    wave 0 from an LDS stage, then wave-local s_waitcnt vmcnt(0) -> add.
//    Only wave 0 sits on the ack path.
//  - out written as 32 x 16B write-through dwordx4 by wave 1, off the arrive
//    path (hides under the poll). Write-through keeps L2 clean for inv.
// ---------------------------------------------------------------------------
__global__ __launch_bounds__(512, 2)
void lstm_persist(const __hip_bfloat16* __restrict__ xb,
                  const __hip_bfloat16* __restrict__ Wxs0, const __hip_bfloat16* __restrict__ Whs0,
                  const __hip_bfloat16* __restrict__ Wxs1, const __hip_bfloat16* __restrict__ Whs1,
                  const float* __restrict__ bih0, const float* __restrict__ bhh0,
                  const float* __restrict__ bih1, const float* __restrict__ bhh1,
                  __hip_bfloat16* __restrict__ h0seq,   // [HD][BH] circular
                  __hip_bfloat16* __restrict__ h1seq,   // [HD][BH] circular
                  float* __restrict__ out,              // [B][T][H]
                  unsigned* __restrict__ cnt)           // arrive counters (128B apart)
{
    const int wg = blockIdx.x, tid = threadIdx.x;
    const int bh = wg >> 7, hg = wg & 127;
    const int wave = tid >> 6, lane = tid & 63;
    const int L = wave >> 2, p = (wave >> 1) & 1, kh = wave & 1;
    const int n = lane & 15, q = lane >> 4;

    __shared__ float psum[2][2][2][16][37];   // [L][p][kh][batch][tau*16+n]
    __shared__ float res[2][128];             // fp32 h0 hand-off for residual
    __shared__ __align__(16) unsigned short hstage[2][16][8];  // bf16 bits [L][b][d]
    __shared__ float houtf[16][8];            // L1 hv fp32 for the out store

    // ---- load B-fragments once, pin in registers ----
    const __hip_bfloat16* Wsel = L ? (p ? Whs1 : Wxs1) : (p ? Whs0 : Wxs0);
    const __bf16* wbp = (const __bf16*)Wsel;

    i32x4_t W0, W1, W2, W3, W4, W5, W6, W7, W8, W9, W10, W11, W12, W13, W14, W15,
            W16, W17, W18, W19, W20, W21, W22, W23, W24, W25, W26, W27, W28, W29, W30, W31;
#define LOADW(IDX, TAU, KB) \
    W##IDX = *(const i32x4_t*)(const void*)(wbp + ((((((size_t)hg * 2 + (TAU)) * 2 + kh) * 16) + (KB)) * 64 + lane) * 8)
    LOADW(0,0,0);  LOADW(1,0,1);  LOADW(2,0,2);  LOADW(3,0,3);
    LOADW(4,0,4);  LOADW(5,0,5);  LOADW(6,0,6);  LOADW(7,0,7);
    LOADW(8,0,8);  LOADW(9,0,9);  LOADW(10,0,10); LOADW(11,0,11);
    LOADW(12,0,12); LOADW(13,0,13); LOADW(14,0,14); LOADW(15,0,15);
    LOADW(16,1,0);  LOADW(17,1,1);  LOADW(18,1,2);  LOADW(19,1,3);
    LOADW(20,1,4);  LOADW(21,1,5);  LOADW(22,1,6);  LOADW(23,1,7);
    LOADW(24,1,8);  LOADW(25,1,9);  LOADW(26,1,10); LOADW(27,1,11);
    LOADW(28,1,12); LOADW(29,1,13); LOADW(30,1,14); LOADW(31,1,15);
#undef LOADW
    asm volatile("" : "+v"(W0), "+v"(W1), "+v"(W2), "+v"(W3),
                      "+v"(W4), "+v"(W5), "+v"(W6), "+v"(W7));
    asm volatile("" : "+v"(W8), "+v"(W9), "+v"(W10), "+v"(W11),
                      "+v"(W12), "+v"(W13), "+v"(W14), "+v"(W15));
    asm volatile("" : "+v"(W16), "+v"(W17), "+v"(W18), "+v"(W19),
                      "+v"(W20), "+v"(W21), "+v"(W22), "+v"(W23));
    asm volatile("" : "+v"(W24), "+v"(W25), "+v"(W26), "+v"(W27),
                      "+v"(W28), "+v"(W29), "+v"(W30), "+v"(W31));

    // ---- pointwise thread state ----
    const int pw_L = tid >> 7, pw_idx = tid & 127, pw_b = (tid >> 3) & 15, pw_d = tid & 7;
    float bias_r[4] = {0.f, 0.f, 0.f, 0.f};
    float c_reg = 0.f;
    if (tid < 256) {
        const float* bi  = pw_L ? bih1 : bih0;
        const float* bh2 = pw_L ? bhh1 : bhh0;
#pragma unroll
        for (int g = 0; g < 4; ++g) {
            int row = g * 1024 + hg * 8 + pw_d;
            bias_r[g] = bi[row] + bh2[row];
        }
    }

    const int arow = bh * 16 + n;
    unsigned* const myc = cnt + bh * 32;     // per-group counter, 128B apart

    // Kernel-start inv: covers cross-launch L1/L2 staleness of h slots read in
    // phases 0..HD-1 (weights already fetched above; inter-kernel release
    // fences wrote shuffle_w's lines back before this dispatch began).
    if (wave == 0)
        asm volatile("buffer_inv sc0 sc1\n\ts_waitcnt vmcnt(0)" ::: "memory");
    __syncthreads();

#define MSTEP(AV, IA, IB) \
    acc0 = __builtin_amdgcn_mfma_f32_16x16x32_bf16(AV, __builtin_bit_cast(bf16x8_t, W##IA), acc0, 0, 0, 0); \
    acc1 = __builtin_amdgcn_mfma_f32_16x16x32_bf16(AV, __builtin_bit_cast(bf16x8_t, W##IB), acc1, 0, 0, 0)
#define CSTEP(KB, IA, IB) { \
    bf16x8_t av = *(const bf16x8_t*)(const void*)(a_base + (KB) * 32); \
    MSTEP(av, IA, IB); }

    for (int t = 0; t <= TT; ++t) {
        // ================= stage 1: GEMMs (plain cached loads; L2 dedups) ====
        const __hip_bfloat16* Abuf;
        if (L == 0) {
            Abuf = p ? (h0seq + (size_t)(t & HMASK) * BH)                  // h0_{t-1}
                     : (xb + (size_t)(t < TT ? t : TT - 1) * BH);
        } else {
            Abuf = p ? (h1seq + (size_t)((t + HD - 1) & HMASK) * BH)       // h1_{t-2}
                     : (h0seq + (size_t)(t & HMASK) * BH);                 // h0_{t-1}
        }
        const __bf16* a_base = (const __bf16*)Abuf + arow * 1024 + kh * 512 + q * 8;

        f32x4_t acc0 = {0.f, 0.f, 0.f, 0.f};
        f32x4_t acc1 = {0.f, 0.f, 0.f, 0.f};
        CSTEP(0,0,16);  CSTEP(1,1,17);  CSTEP(2,2,18);  CSTEP(3,3,19);
        CSTEP(4,4,20);  CSTEP(5,5,21);  CSTEP(6,6,22);  CSTEP(7,7,23);
        CSTEP(8,8,24);  CSTEP(9,9,25);  CSTEP(10,10,26); CSTEP(11,11,27);
        CSTEP(12,12,28); CSTEP(13,13,29); CSTEP(14,14,30); CSTEP(15,15,31);

#pragma unroll
        for (int r = 0; r < 4; ++r) {
            psum[L][p][kh][q * 4 + r][n] = acc0[r];
            psum[L][p][kh][q * 4 + r][16 + n] = acc1[r];
        }
        __syncthreads();   // sync1: psum ready

        // ================= stage 2: pointwise (LDS staging only) =============
        if (tid < 256) {
            const bool active = pw_L ? (t >= 1) : (t < TT);
            if (active) {
                float gv[4];
#pragma unroll
                for (int g = 0; g < 4; ++g) {
                    int col = (g >> 1) * 16 + (g & 1) * 8 + pw_d;
                    gv[g] = psum[pw_L][0][0][pw_b][col] + psum[pw_L][0][1][pw_b][col]
                          + psum[pw_L][1][0][pw_b][col] + psum[pw_L][1][1][pw_b][col]
                          + bias_r[g];
                }
                float si = 1.f / (1.f + __expf(-gv[0]));
                float sf = 1.f / (1.f + __expf(-gv[1]));
                float tg = 2.f / (1.f + __expf(-2.f * gv[2])) - 1.f;
                float so = 1.f / (1.f + __expf(-gv[3]));
                c_reg = sf * c_reg + si * tg;
                float hv = so * (2.f / (1.f + __expf(-2.f * c_reg)) - 1.f);
                __hip_bfloat16 hb16 = __float2bfloat16(hv);
                unsigned short hraw;
                __builtin_memcpy(&hraw, &hb16, 2);
                hstage[pw_L][pw_b][pw_d] = hraw;
                if (pw_L == 0) res[t & 1][pw_idx] = hv;
                else           houtf[pw_b][pw_d] = hv;
            }
        }
        __syncthreads();   // sync2: hstage/houtf/res ready

        // ====== stage 3: wave0 = h stores + ack + arrive; wave1 = out ========
        if (wave == 0) {
            if (tid < 32) {
                const int gl = tid >> 4, b = tid & 15;
                const bool go = gl ? (t >= 1) : (t < TT);
                if (go) {
                    i32x4_t hv16 = *(const i32x4_t*)(const void*)&hstage[gl][b][0];
                    const __hip_bfloat16* dst = gl
                        ? h1seq + ((size_t)(t & HMASK) * BH
                                   + (size_t)(bh * 16 + b) * 1024 + hg * 8)
                        : h0seq + ((size_t)((t + 1) & HMASK) * BH
                                   + (size_t)(bh * 16 + b) * 1024 + hg * 8);
                    asm volatile("global_store_dwordx4 %0, %1, off sc0 sc1"
                                 :: "v"((u64)dst), "v"(hv16) : "memory");
                }
            }
            // wave-local drain: h at the coherence point before the arrive add
            asm volatile("s_waitcnt vmcnt(0)" ::: "memory");
            if (tid == 0 && t < TT)
                __hip_atomic_fetch_add(myc, 1u, __ATOMIC_RELAXED, __HIP_MEMORY_SCOPE_AGENT);
        } else if (wave == 1 && t >= 1) {
            const int j = tid - 64;
            if (j < 32) {
                const int b = j >> 1, hf = j & 1;
                f32x4_t ov;
#pragma unroll
                for (int k = 0; k < 4; ++k)
                    ov[k] = res[(t + 1) & 1][b * 8 + hf * 4 + k] + houtf[b][hf * 4 + k];
                const float* dst = out + (size_t)(bh * 16 + b) * TT * HH
                                       + (size_t)(t - 1) * HH + hg * 8 + hf * 4;
                asm volatile("global_store_dwordx4 %0, %1, off sc0 sc1"
                             :: "v"((u64)dst), "v"(ov) : "memory");
            }
        }

        // ================= stage 4: arrive barrier (1 poller, bounded) =======
        if (tid == 0 && t < TT) {
            const unsigned tgt = (unsigned)(t + 1) * 128u;
            // Safety valve: a correct barrier completes in tens of polls; the
            // 16384 cap (~ms) only fires on a protocol bug, converting a hang
            // into a visible verification failure.
            int spins = 0;
            while (__hip_atomic_load(myc, __ATOMIC_RELAXED,
                                     __HIP_MEMORY_SCOPE_AGENT) < tgt
                   && spins < 16384) {
                __builtin_amdgcn_s_sleep(1);
                ++spins;
            }
        }
        __syncthreads();   // release: all producers of the group have arrived

        // One inv per HD phases, right before the slot cycle wraps.
        if (t < TT && ((t + 1) & HMASK) == 0) {
            if (wave == 0)
                asm volatile("buffer_inv sc0 sc1\n\ts_waitcnt vmcnt(0)" ::: "memory");
            __syncthreads();
        }
    }
#undef MSTEP
#undef CSTEP
}

// ---------------------------------------------------------------------------
// Host side
// ---------------------------------------------------------------------------
extern "C" void kernel_launch(void* const* d_in, const int* in_sizes, int n_in,
                              void* d_out, int out_size, void* d_ws, size_t ws_size,
                              hipStream_t stream) {
    const float* x    = (const float*)d_in[0];
    const float* Wih0 = (const float*)d_in[1];
    const float* Whh0 = (const float*)d_in[2];
    const float* bih0 = (const float*)d_in[3];
    const float* bhh0 = (const float*)d_in[4];
    const float* Wih1 = (const float*)d_in[5];
    const float* Whh1 = (const float*)d_in[6];
    const float* bih1 = (const float*)d_in[7];
    const float* bhh1 = (const float*)d_in[8];
    float* out = (float*)d_out;
    (void)in_sizes; (void)n_in; (void)out_size; (void)ws_size;

    // Workspace carve (~65.0 MiB)
    uint8_t* w = (uint8_t*)d_ws;
    const size_t WMAT = (size_t)G4H * HH * 2;   // 8 MiB bf16 per matrix
    __hip_bfloat16* Wxs0 = (__hip_bfloat16*)(w);
    __hip_bfloat16* Whs0 = (__hip_bfloat16*)(w + WMAT);
    __hip_bfloat16* Wxs1 = (__hip_bfloat16*)(w + 2 * WMAT);
    __hip_bfloat16* Whs1 = (__hip_bfloat16*)(w + 3 * WMAT);
    size_t off = 4 * WMAT;
    __hip_bfloat16* xbuf = (__hip_bfloat16*)(w + off); off += (size_t)TT * BB * II * 2;
    __hip_bfloat16* h0seq = (__hip_bfloat16*)(w + off); off += (size_t)HD * BH * 2;
    __hip_bfloat16* h1seq = (__hip_bfloat16*)(w + off); off += (size_t)HD * BH * 2;
    unsigned* cnt = (unsigned*)(w + off); off += 4096;

    init_bufs<<<256, 256, 0, stream>>>((unsigned*)h0seq, (unsigned*)h1seq, cnt);
    shuffle_w<<<(G4H * HH) / 256, 256, 0, stream>>>(Wih0, Wxs0);
    shuffle_w<<<(G4H * HH) / 256, 256, 0, stream>>>(Whh0, Whs0);
    shuffle_w<<<(G4H * HH) / 256, 256, 0, stream>>>(Wih1, Wxs1);
    shuffle_w<<<(G4H * HH) / 256, 256, 0, stream>>>(Whh1, Whs1);
    convert_x<<<(TT * BB * II) / 256, 256, 0, stream>>>(x, xbuf);

    lstm_persist<<<256, 512, 0, stream>>>(xbuf, Wxs0, Whs0, Wxs1, Whs1,
                                          bih0, bhh0, bih1, bhh1,
                                          h0seq, h1seq, out, cnt);
}

// Round 4
// 3866.008 us; speedup vs baseline: 1.1694x; 1.1694x over previous
//
#include <hip/hip_runtime.h>
#include <hip/hip_bf16.h>

// Problem sizes (fixed)
#define BB 32
#define TT 512
#define HH 1024
#define II 1024
#define G4H 4096
#define BH  (BB * HH)          // 32768
#define HD  8                  // h-buffer depth (slots); buffer_inv every HD phases
#define HMASK (HD - 1)

typedef __bf16 bf16x8_t __attribute__((ext_vector_type(8)));
typedef float f32x4_t __attribute__((ext_vector_type(4)));
typedef int i32x4_t __attribute__((ext_vector_type(4)));
typedef unsigned long long u64;

// ---------------------------------------------------------------------------
// Zero slot 0 of both h sequences + all flag/replica lines, via agent-scope
// (write-through) stores so the zeros are durably at the coherence point.
// (ws re-poisoned 0xAA each call — flags MUST be zeroed or polls mis-release.)
// grid: 256 x 256 = 65536 threads; covers 16384+16384+16384 words.
// ---------------------------------------------------------------------------
__global__ void init_bufs(unsigned* __restrict__ h0w, unsigned* __restrict__ h1w,
                          unsigned* __restrict__ cnt) {
    int i = blockIdx.x * 256 + threadIdx.x;
    if (i < 16384)
        __hip_atomic_store(h0w + i, 0u, __ATOMIC_RELAXED, __HIP_MEMORY_SCOPE_AGENT);
    else if (i < 32768)
        __hip_atomic_store(h1w + (i - 16384), 0u, __ATOMIC_RELAXED, __HIP_MEMORY_SCOPE_AGENT);
    else if (i < 49152)
        __hip_atomic_store(cnt + (i - 32768), 0u, __ATOMIC_RELAXED, __HIP_MEMORY_SCOPE_AGENT);
}

// ---------------------------------------------------------------------------
// Weight shuffle: fp32 [4096][1024] -> bf16 B-fragment order. (unchanged)
// ---------------------------------------------------------------------------
__global__ void shuffle_w(const float* __restrict__ src, __hip_bfloat16* __restrict__ dst) {
    size_t i = (size_t)blockIdx.x * 256 + threadIdx.x;   // 0 .. 4M-1
    int jj   = (int)(i & 7);
    int lane = (int)((i >> 3) & 63);
    int kb   = (int)((i >> 9) & 15);
    int kh   = (int)((i >> 13) & 1);
    int tau  = (int)((i >> 14) & 1);
    int hg   = (int)(i >> 15);
    int n = lane & 15, q = lane >> 4;
    int row = (2 * tau + (n >> 3)) * 1024 + hg * 8 + (n & 7);
    int col = kh * 512 + kb * 32 + q * 8 + jj;
    dst[i] = __float2bfloat16(src[(size_t)row * II + col]);
}

// ---------------------------------------------------------------------------
// x [B][T][I] fp32 -> xb [T][B][I] bf16 (unchanged)
// ---------------------------------------------------------------------------
__global__ void convert_x(const float* __restrict__ x, __hip_bfloat16* __restrict__ xb) {
    size_t i = (size_t)blockIdx.x * 256 + threadIdx.x;   // T*B*I
    int ii = (int)(i & 1023);
    int b  = (int)((i >> 10) & 31);
    int t  = (int)(i >> 15);
    xb[i] = __float2bfloat16(x[((size_t)b * TT + t) * II + ii]);
}

// ---------------------------------------------------------------------------
// Persistent fused 2-layer LSTM. 256 WGs (1/CU) x 512 threads (8 waves).
//
// RESUBMIT of the round-3 design (container died before it ran; the kernel is
// spin-capped everywhere so it cannot hang — a protocol bug would have shown
// as passed:false, not a dead container).
//
// Theory under test: rounds 0/2 saturated the MALL banks holding the barrier
// lines (r0: 128 pollers per flag line; r2: 128 RMWs + 128 pollers on ONE
// counter line). Arrive traffic queued behind poll storms -> several µs of
// invisible barrier cost per phase. Fix: TREE barrier with replicated
// release so every polled line has <= 8 pollers:
//   arrive : each WG stores flag[wg] = t+1 (own line; 1 writer, 1 poller)
//   detect : master WG (hg == bh, distinct XCDs) polls all 128 group flags
//            with 128 threads -> exactly 1 poller per line
//   release: master stores t+1 to 16 replica lines; WG hg polls replica
//            (hg & 15) -> 8 pollers per replica line
// Replica same-line store ordering across phases is guaranteed by wave0's
// vmcnt(0) drain in stage 3 (drains the previous replica store before the
// next one is issued) -> values on a replica line are monotone.
// Kept from round 2 (worked: FETCH 480->411 MB): depth-8 h slots + ONE
// buffer_inv per 8 phases; 32x16B batched write-through h stores by wave 0;
// out stores by wave 1 off the arrive path. Bounded spins = hang safety.
// ---------------------------------------------------------------------------
__global__ __launch_bounds__(512, 2)
void lstm_persist(const __hip_bfloat16* __restrict__ xb,
                  const __hip_bfloat16* __restrict__ Wxs0, const __hip_bfloat16* __restrict__ Whs0,
                  const __hip_bfloat16* __restrict__ Wxs1, const __hip_bfloat16* __restrict__ Whs1,
                  const float* __restrict__ bih0, const float* __restrict__ bhh0,
                  const float* __restrict__ bih1, const float* __restrict__ bhh1,
                  __hip_bfloat16* __restrict__ h0seq,   // [HD][BH] circular
                  __hip_bfloat16* __restrict__ h1seq,   // [HD][BH] circular
                  float* __restrict__ out,              // [B][T][H]
                  unsigned* __restrict__ cnt)           // flag/replica lines, 128B stride
{
    const int wg = blockIdx.x, tid = threadIdx.x;
    const int bh = wg >> 7, hg = wg & 127;
    const int wave = tid >> 6, lane = tid & 63;
    const int L = wave >> 2, p = (wave >> 1) & 1, kh = wave & 1;
    const int n = lane & 15, q = lane >> 4;

    __shared__ float psum[2][2][2][16][37];   // [L][p][kh][batch][tau*16+n]
    __shared__ float res[2][128];             // fp32 h0 hand-off for residual
    __shared__ __align__(16) unsigned short hstage[2][16][8];  // bf16 bits [L][b][d]
    __shared__ float houtf[16][8];            // L1 hv fp32 for the out store

    // ---- load B-fragments once, pin in registers ----
    const __hip_bfloat16* Wsel = L ? (p ? Whs1 : Wxs1) : (p ? Whs0 : Wxs0);
    const __bf16* wbp = (const __bf16*)Wsel;

    i32x4_t W0, W1, W2, W3, W4, W5, W6, W7, W8, W9, W10, W11, W12, W13, W14, W15,
            W16, W17, W18, W19, W20, W21, W22, W23, W24, W25, W26, W27, W28, W29, W30, W31;
#define LOADW(IDX, TAU, KB) \
    W##IDX = *(const i32x4_t*)(const void*)(wbp + ((((((size_t)hg * 2 + (TAU)) * 2 + kh) * 16) + (KB)) * 64 + lane) * 8)
    LOADW(0,0,0);  LOADW(1,0,1);  LOADW(2,0,2);  LOADW(3,0,3);
    LOADW(4,0,4);  LOADW(5,0,5);  LOADW(6,0,6);  LOADW(7,0,7);
    LOADW(8,0,8);  LOADW(9,0,9);  LOADW(10,0,10); LOADW(11,0,11);
    LOADW(12,0,12); LOADW(13,0,13); LOADW(14,0,14); LOADW(15,0,15);
    LOADW(16,1,0);  LOADW(17,1,1);  LOADW(18,1,2);  LOADW(19,1,3);
    LOADW(20,1,4);  LOADW(21,1,5);  LOADW(22,1,6);  LOADW(23,1,7);
    LOADW(24,1,8);  LOADW(25,1,9);  LOADW(26,1,10); LOADW(27,1,11);
    LOADW(28,1,12); LOADW(29,1,13); LOADW(30,1,14); LOADW(31,1,31 - 16);
#undef LOADW
    asm volatile("" : "+v"(W0), "+v"(W1), "+v"(W2), "+v"(W3),
                      "+v"(W4), "+v"(W5), "+v"(W6), "+v"(W7));
    asm volatile("" : "+v"(W8), "+v"(W9), "+v"(W10), "+v"(W11),
                      "+v"(W12), "+v"(W13), "+v"(W14), "+v"(W15));
    asm volatile("" : "+v"(W16), "+v"(W17), "+v"(W18), "+v"(W19),
                      "+v"(W20), "+v"(W21), "+v"(W22), "+v"(W23));
    asm volatile("" : "+v"(W24), "+v"(W25), "+v"(W26), "+v"(W27),
                      "+v"(W28), "+v"(W29), "+v"(W30), "+v"(W31));

    // ---- pointwise thread state ----
    const int pw_L = tid >> 7, pw_idx = tid & 127, pw_b = (tid >> 3) & 15, pw_d = tid & 7;
    float bias_r[4] = {0.f, 0.f, 0.f, 0.f};
    float c_reg = 0.f;
    if (tid < 256) {
        const float* bi  = pw_L ? bih1 : bih0;
        const float* bh2 = pw_L ? bhh1 : bhh0;
#pragma unroll
        for (int g = 0; g < 4; ++g) {
            int row = g * 1024 + hg * 8 + pw_d;
            bias_r[g] = bi[row] + bh2[row];
        }
    }

    const int arow = bh * 16 + n;
    const bool is_master = (hg == bh);     // masters on XCD 0 and XCD 1

    // Kernel-start inv: covers cross-launch L1/L2 staleness of h slots read in
    // phases 0..HD-1.
    if (wave == 0)
        asm volatile("buffer_inv sc0 sc1\n\ts_waitcnt vmcnt(0)" ::: "memory");
    __syncthreads();

#define MSTEP(AV, IA, IB) \
    acc0 = __builtin_amdgcn_mfma_f32_16x16x32_bf16(AV, __builtin_bit_cast(bf16x8_t, W##IA), acc0, 0, 0, 0); \
    acc1 = __builtin_amdgcn_mfma_f32_16x16x32_bf16(AV, __builtin_bit_cast(bf16x8_t, W##IB), acc1, 0, 0, 0)
#define CSTEP(KB, IA, IB) { \
    bf16x8_t av = *(const bf16x8_t*)(const void*)(a_base + (KB) * 32); \
    MSTEP(av, IA, IB); }

    for (int t = 0; t <= TT; ++t) {
        // ================= stage 1: GEMMs (plain cached loads; L2 dedups) ====
        const __hip_bfloat16* Abuf;
        if (L == 0) {
            Abuf = p ? (h0seq + (size_t)(t & HMASK) * BH)                  // h0_{t-1}
                     : (xb + (size_t)(t < TT ? t : TT - 1) * BH);
        } else {
            Abuf = p ? (h1seq + (size_t)((t + HD - 1) & HMASK) * BH)       // h1_{t-2}
                     : (h0seq + (size_t)(t & HMASK) * BH);                 // h0_{t-1}
        }
        const __bf16* a_base = (const __bf16*)Abuf + arow * 1024 + kh * 512 + q * 8;

        f32x4_t acc0 = {0.f, 0.f, 0.f, 0.f};
        f32x4_t acc1 = {0.f, 0.f, 0.f, 0.f};
        CSTEP(0,0,16);  CSTEP(1,1,17);  CSTEP(2,2,18);  CSTEP(3,3,19);
        CSTEP(4,4,20);  CSTEP(5,5,21);  CSTEP(6,6,22);  CSTEP(7,7,23);
        CSTEP(8,8,24);  CSTEP(9,9,25);  CSTEP(10,10,26); CSTEP(11,11,27);
        CSTEP(12,12,28); CSTEP(13,13,29); CSTEP(14,14,30); CSTEP(15,15,31);

#pragma unroll
        for (int r = 0; r < 4; ++r) {
            psum[L][p][kh][q * 4 + r][n] = acc0[r];
            psum[L][p][kh][q * 4 + r][16 + n] = acc1[r];
        }
        __syncthreads();   // sync1: psum ready

        // ================= stage 2: pointwise (LDS staging only) =============
        if (tid < 256) {
            const bool active = pw_L ? (t >= 1) : (t < TT);
            if (active) {
                float gv[4];
#pragma unroll
                for (int g = 0; g < 4; ++g) {
                    int col = (g >> 1) * 16 + (g & 1) * 8 + pw_d;
                    gv[g] = psum[pw_L][0][0][pw_b][col] + psum[pw_L][0][1][pw_b][col]
                          + psum[pw_L][1][0][pw_b][col] + psum[pw_L][1][1][pw_b][col]
                          + bias_r[g];
                }
                float si = 1.f / (1.f + __expf(-gv[0]));
                float sf = 1.f / (1.f + __expf(-gv[1]));
                float tg = 2.f / (1.f + __expf(-2.f * gv[2])) - 1.f;
                float so = 1.f / (1.f + __expf(-gv[3]));
                c_reg = sf * c_reg + si * tg;
                float hv = so * (2.f / (1.f + __expf(-2.f * c_reg)) - 1.f);
                __hip_bfloat16 hb16 = __float2bfloat16(hv);
                unsigned short hraw;
                __builtin_memcpy(&hraw, &hb16, 2);
                hstage[pw_L][pw_b][pw_d] = hraw;
                if (pw_L == 0) res[t & 1][pw_idx] = hv;
                else           houtf[pw_b][pw_d] = hv;
            }
        }
        __syncthreads();   // sync2: hstage/houtf/res ready

        // ====== stage 3: wave0 = h stores + ack + arrive; wave1 = out ========
        if (wave == 0) {
            if (tid < 32) {
                const int gl = tid >> 4, b = tid & 15;
                const bool go = gl ? (t >= 1) : (t < TT);
                if (go) {
                    i32x4_t hv16 = *(const i32x4_t*)(const void*)&hstage[gl][b][0];
                    const __hip_bfloat16* dst = gl
                        ? h1seq + ((size_t)(t & HMASK) * BH
                                   + (size_t)(bh * 16 + b) * 1024 + hg * 8)
                        : h0seq + ((size_t)((t + 1) & HMASK) * BH
                                   + (size_t)(bh * 16 + b) * 1024 + hg * 8);
                    asm volatile("global_store_dwordx4 %0, %1, off sc0 sc1"
                                 :: "v"((u64)dst), "v"(hv16) : "memory");
                }
            }
            // wave-local drain: h at coherence point before the arrive store.
            // (Also drains the previous phase's replica stores on the master ->
            //  replica-line values stay monotone.)
            asm volatile("s_waitcnt vmcnt(0)" ::: "memory");
            if (tid == 0 && t < TT)
                __hip_atomic_store(cnt + (size_t)wg * 32, (unsigned)(t + 1),
                                   __ATOMIC_RELAXED, __HIP_MEMORY_SCOPE_AGENT);
        } else if (wave == 1 && t >= 1) {
            const int j = tid - 64;
            if (j < 32) {
                const int b = j >> 1, hf = j & 1;
                f32x4_t ov;
#pragma unroll
                for (int k = 0; k < 4; ++k)
                    ov[k] = res[(t + 1) & 1][b * 8 + hf * 4 + k] + houtf[b][hf * 4 + k];
                const float* dst = out + (size_t)(bh * 16 + b) * TT * HH
                                       + (size_t)(t - 1) * HH + hg * 8 + hf * 4;
                asm volatile("global_store_dwordx4 %0, %1, off sc0 sc1"
                             :: "v"((u64)dst), "v"(ov) : "memory");
            }
        }

        // ========== stage 4: tree barrier (1 poller per flag line) ===========
        if (t < TT) {
            const unsigned tgt = (unsigned)(t + 1);
            if (is_master) {
                // master: 128 threads poll the group's 128 flags (1 line each)
                if (tid < 128) {
                    const unsigned* fl = cnt + (size_t)(bh * 128 + tid) * 32;
                    int spins = 0;
                    while (__hip_atomic_load(fl, __ATOMIC_RELAXED,
                                             __HIP_MEMORY_SCOPE_AGENT) < tgt
                           && spins < 8192) {
                        __builtin_amdgcn_s_sleep(1);
                        ++spins;
                    }
                }
                __syncthreads();   // all flags seen
                // release: replicate to 16 lines (8 consumer-pollers each)
                if (tid < 16)
                    __hip_atomic_store(cnt + (size_t)(256 + bh * 16 + tid) * 32, tgt,
                                       __ATOMIC_RELAXED, __HIP_MEMORY_SCOPE_AGENT);
            } else {
                if (tid == 0) {
                    const unsigned* rl = cnt + (size_t)(256 + bh * 16 + (hg & 15)) * 32;
                    int spins = 0;
                    while (__hip_atomic_load(rl, __ATOMIC_RELAXED,
                                             __HIP_MEMORY_SCOPE_AGENT) < tgt
                           && spins < 8192) {
                        __builtin_amdgcn_s_sleep(1);
                        ++spins;
                    }
                }
                __syncthreads();   // WG released
            }

            // One inv per HD phases, right before the slot cycle wraps.
            if (((t + 1) & HMASK) == 0) {
                if (wave == 0)
                    asm volatile("buffer_inv sc0 sc1\n\ts_waitcnt vmcnt(0)" ::: "memory");
                __syncthreads();
            }
        }
    }
#undef MSTEP
#undef CSTEP
}

// ---------------------------------------------------------------------------
// Host side
// ---------------------------------------------------------------------------
extern "C" void kernel_launch(void* const* d_in, const int* in_sizes, int n_in,
                              void* d_out, int out_size, void* d_ws, size_t ws_size,
                              hipStream_t stream) {
    const float* x    = (const float*)d_in[0];
    const float* Wih0 = (const float*)d_in[1];
    const float* Whh0 = (const float*)d_in[2];
    const float* bih0 = (const float*)d_in[3];
    const float* bhh0 = (const float*)d_in[4];
    const float* Wih1 = (const float*)d_in[5];
    const float* Whh1 = (const float*)d_in[6];
    const float* bih1 = (const float*)d_in[7];
    const float* bhh1 = (const float*)d_in[8];
    float* out = (float*)d_out;
    (void)in_sizes; (void)n_in; (void)out_size; (void)ws_size;

    // Workspace carve (~65.1 MiB)
    uint8_t* w = (uint8_t*)d_ws;
    const size_t WMAT = (size_t)G4H * HH * 2;   // 8 MiB bf16 per matrix
    __hip_bfloat16* Wxs0 = (__hip_bfloat16*)(w);
    __hip_bfloat16* Whs0 = (__hip_bfloat16*)(w + WMAT);
    __hip_bfloat16* Wxs1 = (__hip_bfloat16*)(w + 2 * WMAT);
    __hip_bfloat16* Whs1 = (__hip_bfloat16*)(w + 3 * WMAT);
    size_t off = 4 * WMAT;
    __hip_bfloat16* xbuf = (__hip_bfloat16*)(w + off); off += (size_t)TT * BB * II * 2;
    __hip_bfloat16* h0seq = (__hip_bfloat16*)(w + off); off += (size_t)HD * BH * 2;
    __hip_bfloat16* h1seq = (__hip_bfloat16*)(w + off); off += (size_t)HD * BH * 2;
    unsigned* cnt = (unsigned*)(w + off); off += 65536;   // 16K words of lines

    init_bufs<<<256, 256, 0, stream>>>((unsigned*)h0seq, (unsigned*)h1seq, cnt);
    shuffle_w<<<(G4H * HH) / 256, 256, 0, stream>>>(Wih0, Wxs0);
    shuffle_w<<<(G4H * HH) / 256, 256, 0, stream>>>(Whh0, Whs0);
    shuffle_w<<<(G4H * HH) / 256, 256, 0, stream>>>(Wih1, Wxs1);
    shuffle_w<<<(G4H * HH) / 256, 256, 0, stream>>>(Whh1, Whs1);
    convert_x<<<(TT * BB * II) / 256, 256, 0, stream>>>(x, xbuf);

    lstm_persist<<<256, 512, 0, stream>>>(xbuf, Wxs0, Whs0, Wxs1, Whs1,
                                          bih0, bhh0, bih1, bhh1,
                                          h0seq, h1seq, out, cnt);
}

// Round 5
// 2880.398 us; speedup vs baseline: 1.5696x; 1.3422x over previous
//
#include <hip/hip_runtime.h>
#include <hip/hip_bf16.h>

// Problem sizes (fixed)
#define BB 32
#define TT 512
#define HH 1024
#define II 1024
#define G4H 4096
#define BH  (BB * HH)          // 32768
#define HD  8                  // h-buffer depth (slots); buffer_inv every HD phases
#define HMASK (HD - 1)

typedef __bf16 bf16x8_t __attribute__((ext_vector_type(8)));
typedef float f32x4_t __attribute__((ext_vector_type(4)));
typedef int i32x4_t __attribute__((ext_vector_type(4)));
typedef unsigned long long u64;

// async global(16B/lane) -> LDS(base + lane*16); size/offset/aux are literals
__device__ __forceinline__ void gload16(const void* g, void* l) {
    __builtin_amdgcn_global_load_lds(
        (const __attribute__((address_space(1))) unsigned int*)g,
        (__attribute__((address_space(3))) unsigned int*)l, 16, 0, 0);
}

// ---------------------------------------------------------------------------
// Zero slot 0 of both h sequences + all flag/replica lines, via agent-scope
// (write-through) stores so the zeros are durably at the coherence point.
// (ws re-poisoned 0xAA each call — flags MUST be zeroed or polls mis-release.)
// ---------------------------------------------------------------------------
__global__ void init_bufs(unsigned* __restrict__ h0w, unsigned* __restrict__ h1w,
                          unsigned* __restrict__ cnt) {
    int i = blockIdx.x * 256 + threadIdx.x;
    if (i < 16384)
        __hip_atomic_store(h0w + i, 0u, __ATOMIC_RELAXED, __HIP_MEMORY_SCOPE_AGENT);
    else if (i < 32768)
        __hip_atomic_store(h1w + (i - 16384), 0u, __ATOMIC_RELAXED, __HIP_MEMORY_SCOPE_AGENT);
    else if (i < 49152)
        __hip_atomic_store(cnt + (i - 32768), 0u, __ATOMIC_RELAXED, __HIP_MEMORY_SCOPE_AGENT);
}

// ---------------------------------------------------------------------------
// Weight shuffle: fp32 [4096][1024] -> bf16 B-fragment order. (unchanged)
// ---------------------------------------------------------------------------
__global__ void shuffle_w(const float* __restrict__ src, __hip_bfloat16* __restrict__ dst) {
    size_t i = (size_t)blockIdx.x * 256 + threadIdx.x;   // 0 .. 4M-1
    int jj   = (int)(i & 7);
    int lane = (int)((i >> 3) & 63);
    int kb   = (int)((i >> 9) & 15);
    int kh   = (int)((i >> 13) & 1);
    int tau  = (int)((i >> 14) & 1);
    int hg   = (int)(i >> 15);
    int n = lane & 15, q = lane >> 4;
    int row = (2 * tau + (n >> 3)) * 1024 + hg * 8 + (n & 7);
    int col = kh * 512 + kb * 32 + q * 8 + jj;
    dst[i] = __float2bfloat16(src[(size_t)row * II + col]);
}

// ---------------------------------------------------------------------------
// x [B][T][I] fp32 -> xb [T][B][I] bf16 (unchanged)
// ---------------------------------------------------------------------------
__global__ void convert_x(const float* __restrict__ x, __hip_bfloat16* __restrict__ xb) {
    size_t i = (size_t)blockIdx.x * 256 + threadIdx.x;   // T*B*I
    int ii = (int)(i & 1023);
    int b  = (int)((i >> 10) & 31);
    int t  = (int)(i >> 15);
    xb[i] = __float2bfloat16(x[((size_t)b * TT + t) * II + ii]);
}

// ---------------------------------------------------------------------------
// Persistent fused 2-layer LSTM. 256 WGs (1/CU) x 512 threads (8 waves).
//
// Round-5 change (theory: the shared ~7.3 µs/phase floor across 3 barrier
// designs is the GEMM A-load path — per-CSTEP global loads with only ~36
// free VGPRs serialize into 2+ IF-latency batches, plus h0 loaded twice):
//  - stage 0: ALL A-streams DMA'd to LDS via global_load_lds (16 B/lane,
//    16 outstanding per stream -> single latency exposure, zero VGPR cost).
//    6 unique 16KB streams: x|kh, h0|kh, h1|kh. h0 staged ONCE, read by 4
//    waves (was loaded twice) -> per-WG global A-traffic 128->96 KB.
//  - x-streams don't depend on the barrier: issued in stage 3 AFTER the
//    arrive store, so they complete during the release poll (off-phase).
//  - stage 1 reads fragments from LDS (ds_read_b128, dense conflict-free).
// Kept: tree barrier (r4), depth-8 h slots + ONE buffer_inv per 8 phases,
// 32x16B write-through h stores + wave-local vmcnt drain before arrive,
// out stores by wave 1 off the arrive path, bounded spins as hang safety.
// LDS: 96 KB astage + ~21 KB psum/res/stage = ~119 KB (<160 KB/CU gfx950).
// ---------------------------------------------------------------------------
__global__ __launch_bounds__(512, 2)
void lstm_persist(const __hip_bfloat16* __restrict__ xb,
                  const __hip_bfloat16* __restrict__ Wxs0, const __hip_bfloat16* __restrict__ Whs0,
                  const __hip_bfloat16* __restrict__ Wxs1, const __hip_bfloat16* __restrict__ Whs1,
                  const float* __restrict__ bih0, const float* __restrict__ bhh0,
                  const float* __restrict__ bih1, const float* __restrict__ bhh1,
                  __hip_bfloat16* __restrict__ h0seq,   // [HD][BH] circular
                  __hip_bfloat16* __restrict__ h1seq,   // [HD][BH] circular
                  float* __restrict__ out,              // [B][T][H]
                  unsigned* __restrict__ cnt)           // flag/replica lines, 128B stride
{
    const int wg = blockIdx.x, tid = threadIdx.x;
    const int bh = wg >> 7, hg = wg & 127;
    const int wave = tid >> 6, lane = tid & 63;
    const int L = wave >> 2, p = (wave >> 1) & 1, kh = wave & 1;
    const int n = lane & 15, q = lane >> 4;

    __shared__ float psum[2][2][2][16][37];   // [L][p][kh][batch][tau*16+n]
    __shared__ float res[2][128];             // fp32 h0 hand-off for residual
    __shared__ __align__(16) unsigned short hstage[2][16][8];  // bf16 bits [L][b][d]
    __shared__ float houtf[16][8];            // L1 hv fp32 for the out store
    // A-fragment staging: 6 streams x 16 KB (stream: 0,1=x|kh 2,3=h0|kh 4,5=h1|kh)
    __shared__ __align__(16) char astage[6 * 16384];

    // ---- load B-fragments once, pin in registers ----
    const __hip_bfloat16* Wsel = L ? (p ? Whs1 : Wxs1) : (p ? Whs0 : Wxs0);
    const __bf16* wbp = (const __bf16*)Wsel;

    i32x4_t W0, W1, W2, W3, W4, W5, W6, W7, W8, W9, W10, W11, W12, W13, W14, W15,
            W16, W17, W18, W19, W20, W21, W22, W23, W24, W25, W26, W27, W28, W29, W30, W31;
#define LOADW(IDX, TAU, KB) \
    W##IDX = *(const i32x4_t*)(const void*)(wbp + ((((((size_t)hg * 2 + (TAU)) * 2 + kh) * 16) + (KB)) * 64 + lane) * 8)
    LOADW(0,0,0);  LOADW(1,0,1);  LOADW(2,0,2);  LOADW(3,0,3);
    LOADW(4,0,4);  LOADW(5,0,5);  LOADW(6,0,6);  LOADW(7,0,7);
    LOADW(8,0,8);  LOADW(9,0,9);  LOADW(10,0,10); LOADW(11,0,11);
    LOADW(12,0,12); LOADW(13,0,13); LOADW(14,0,14); LOADW(15,0,15);
    LOADW(16,1,0);  LOADW(17,1,1);  LOADW(18,1,2);  LOADW(19,1,3);
    LOADW(20,1,4);  LOADW(21,1,5);  LOADW(22,1,6);  LOADW(23,1,7);
    LOADW(24,1,8);  LOADW(25,1,9);  LOADW(26,1,10); LOADW(27,1,11);
    LOADW(28,1,12); LOADW(29,1,13); LOADW(30,1,14); LOADW(31,1,15);
#undef LOADW
    asm volatile("" : "+v"(W0), "+v"(W1), "+v"(W2), "+v"(W3),
                      "+v"(W4), "+v"(W5), "+v"(W6), "+v"(W7));
    asm volatile("" : "+v"(W8), "+v"(W9), "+v"(W10), "+v"(W11),
                      "+v"(W12), "+v"(W13), "+v"(W14), "+v"(W15));
    asm volatile("" : "+v"(W16), "+v"(W17), "+v"(W18), "+v"(W19),
                      "+v"(W20), "+v"(W21), "+v"(W22), "+v"(W23));
    asm volatile("" : "+v"(W24), "+v"(W25), "+v"(W26), "+v"(W27),
                      "+v"(W28), "+v"(W29), "+v"(W30), "+v"(W31));

    // ---- pointwise thread state ----
    const int pw_L = tid >> 7, pw_idx = tid & 127, pw_b = (tid >> 3) & 15, pw_d = tid & 7;
    float bias_r[4] = {0.f, 0.f, 0.f, 0.f};
    float c_reg = 0.f;
    if (tid < 256) {
        const float* bi  = pw_L ? bih1 : bih0;
        const float* bh2 = pw_L ? bhh1 : bhh0;
#pragma unroll
        for (int g = 0; g < 4; ++g) {
            int row = g * 1024 + hg * 8 + pw_d;
            bias_r[g] = bi[row] + bh2[row];
        }
    }

    const int arow = bh * 16 + n;
    const bool is_master = (hg == bh);     // masters on distinct XCDs

    // this wave's read-stream base in astage
    const int sread = (L == 0) ? (p == 0 ? kh : 2 + kh)
                               : (p == 0 ? 2 + kh : 4 + kh);
    const char* const rdbase = astage + sread * 16384 + lane * 16;

    // Kernel-start inv: covers cross-launch L1/L2 staleness of h slots read in
    // phases 0..HD-1.
    if (wave == 0)
        asm volatile("buffer_inv sc0 sc1\n\ts_waitcnt vmcnt(0)" ::: "memory");
    __syncthreads();

    // prologue: preload x slice 0 (streams 0,1); landed by the first sync0
    if (wave < 2) {
        const __bf16* gx = (const __bf16*)xb + arow * 1024 + kh * 512 + q * 8;
        char* ldx = astage + kh * 16384;
#pragma unroll
        for (int kb2 = 0; kb2 < 16; ++kb2)
            gload16(gx + kb2 * 32, ldx + kb2 * 1024);
    }

#define MSTEP(AV, IA, IB) \
    acc0 = __builtin_amdgcn_mfma_f32_16x16x32_bf16(AV, __builtin_bit_cast(bf16x8_t, W##IA), acc0, 0, 0, 0); \
    acc1 = __builtin_amdgcn_mfma_f32_16x16x32_bf16(AV, __builtin_bit_cast(bf16x8_t, W##IB), acc1, 0, 0, 0)
#define CSTEP(KB, IA, IB) { \
    bf16x8_t av = *(const bf16x8_t*)(const void*)(rdbase + (KB) * 1024); \
    MSTEP(av, IA, IB); }

    for (int t = 0; t <= TT; ++t) {
        // ========== stage 0: DMA h-streams to LDS (x prefetched last phase) ==
        if (p == 1) {
            const __hip_bfloat16* Ad = (L == 0)
                ? h0seq + (size_t)(t & HMASK) * BH                   // h0_{t-1}
                : h1seq + (size_t)((t + HD - 1) & HMASK) * BH;       // h1_{t-2}
            const __bf16* gsrc = (const __bf16*)Ad + arow * 1024 + kh * 512 + q * 8;
            char* ldst = astage + ((L == 0 ? 2 : 4) + kh) * 16384;
#pragma unroll
            for (int kb2 = 0; kb2 < 16; ++kb2)
                gload16(gsrc + kb2 * 32, ldst + kb2 * 1024);
        }
        __syncthreads();   // sync0: drains vmcnt -> all staged data visible

        // ================= stage 1: GEMMs from LDS ===========================
        f32x4_t acc0 = {0.f, 0.f, 0.f, 0.f};
        f32x4_t acc1 = {0.f, 0.f, 0.f, 0.f};
        CSTEP(0,0,16);  CSTEP(1,1,17);  CSTEP(2,2,18);  CSTEP(3,3,19);
        CSTEP(4,4,20);  CSTEP(5,5,21);  CSTEP(6,6,22);  CSTEP(7,7,23);
        CSTEP(8,8,24);  CSTEP(9,9,25);  CSTEP(10,10,26); CSTEP(11,11,27);
        CSTEP(12,12,28); CSTEP(13,13,29); CSTEP(14,14,30); CSTEP(15,15,31);

#pragma unroll
        for (int r = 0; r < 4; ++r) {
            psum[L][p][kh][q * 4 + r][n] = acc0[r];
            psum[L][p][kh][q * 4 + r][16 + n] = acc1[r];
        }
        __syncthreads();   // sync1: psum ready

        // ================= stage 2: pointwise (LDS staging only) =============
        if (tid < 256) {
            const bool active = pw_L ? (t >= 1) : (t < TT);
            if (active) {
                float gv[4];
#pragma unroll
                for (int g = 0; g < 4; ++g) {
                    int col = (g >> 1) * 16 + (g & 1) * 8 + pw_d;
                    gv[g] = psum[pw_L][0][0][pw_b][col] + psum[pw_L][0][1][pw_b][col]
                          + psum[pw_L][1][0][pw_b][col] + psum[pw_L][1][1][pw_b][col]
                          + bias_r[g];
                }
                float si = 1.f / (1.f + __expf(-gv[0]));
                float sf = 1.f / (1.f + __expf(-gv[1]));
                float tg = 2.f / (1.f + __expf(-2.f * gv[2])) - 1.f;
                float so = 1.f / (1.f + __expf(-gv[3]));
                c_reg = sf * c_reg + si * tg;
                float hv = so * (2.f / (1.f + __expf(-2.f * c_reg)) - 1.f);
                __hip_bfloat16 hb16 = __float2bfloat16(hv);
                unsigned short hraw;
                __builtin_memcpy(&hraw, &hb16, 2);
                hstage[pw_L][pw_b][pw_d] = hraw;
                if (pw_L == 0) res[t & 1][pw_idx] = hv;
                else           houtf[pw_b][pw_d] = hv;
            }
        }
        __syncthreads();   // sync2: hstage/houtf/res ready

        // == stage 3: wave0 = h stores + ack + arrive + x-DMA; wave1 = out ====
        if (wave == 0) {
            if (tid < 32) {
                const int gl = tid >> 4, b = tid & 15;
                const bool go = gl ? (t >= 1) : (t < TT);
                if (go) {
                    i32x4_t hv16 = *(const i32x4_t*)(const void*)&hstage[gl][b][0];
                    const __hip_bfloat16* dst = gl
                        ? h1seq + ((size_t)(t & HMASK) * BH
                                   + (size_t)(bh * 16 + b) * 1024 + hg * 8)
                        : h0seq + ((size_t)((t + 1) & HMASK) * BH
                                   + (size_t)(bh * 16 + b) * 1024 + hg * 8);
                    asm volatile("global_store_dwordx4 %0, %1, off sc0 sc1"
                                 :: "v"((u64)dst), "v"(hv16) : "memory");
                }
            }
            // wave-local drain: h at coherence point before the arrive store.
            asm volatile("s_waitcnt vmcnt(0)" ::: "memory");
            if (tid == 0 && t < TT)
                __hip_atomic_store(cnt + (size_t)wg * 32, (unsigned)(t + 1),
                                   __ATOMIC_RELAXED, __HIP_MEMORY_SCOPE_AGENT);
            // x-DMA for phase t+1 (kh=0), AFTER the arrive: flies under the poll
            if (t < TT) {
                const int tn = (t + 1 < TT) ? (t + 1) : (TT - 1);
                const __bf16* gx = (const __bf16*)xb + (size_t)tn * BH
                                   + arow * 1024 + q * 8;
                char* ldx = astage;
#pragma unroll
                for (int kb2 = 0; kb2 < 16; ++kb2)
                    gload16(gx + kb2 * 32, ldx + kb2 * 1024);
            }
        } else if (wave == 1) {
            if (t >= 1) {
                const int j = tid - 64;
                if (j < 32) {
                    const int b = j >> 1, hf = j & 1;
                    f32x4_t ov;
#pragma unroll
                    for (int k = 0; k < 4; ++k)
                        ov[k] = res[(t + 1) & 1][b * 8 + hf * 4 + k] + houtf[b][hf * 4 + k];
                    const float* dst = out + (size_t)(bh * 16 + b) * TT * HH
                                           + (size_t)(t - 1) * HH + hg * 8 + hf * 4;
                    asm volatile("global_store_dwordx4 %0, %1, off sc0 sc1"
                                 :: "v"((u64)dst), "v"(ov) : "memory");
                }
            }
            // x-DMA for phase t+1 (kh=1)
            if (t < TT) {
                const int tn = (t + 1 < TT) ? (t + 1) : (TT - 1);
                const __bf16* gx = (const __bf16*)xb + (size_t)tn * BH
                                   + arow * 1024 + 512 + q * 8;
                char* ldx = astage + 16384;
#pragma unroll
                for (int kb2 = 0; kb2 < 16; ++kb2)
                    gload16(gx + kb2 * 32, ldx + kb2 * 1024);
            }
        }

        // ========== stage 4: tree barrier (1 poller per flag line) ===========
        if (t < TT) {
            const unsigned tgt = (unsigned)(t + 1);
            if (is_master) {
                // master: 128 threads poll the group's 128 flags (1 line each)
                if (tid < 128) {
                    const unsigned* fl = cnt + (size_t)(bh * 128 + tid) * 32;
                    int spins = 0;
                    while (__hip_atomic_load(fl, __ATOMIC_RELAXED,
                                             __HIP_MEMORY_SCOPE_AGENT) < tgt
                           && spins < 8192) {
                        __builtin_amdgcn_s_sleep(1);
                        ++spins;
                    }
                }
                __syncthreads();   // all flags seen
                // release: replicate to 16 lines (8 consumer-pollers each)
                if (tid < 16)
                    __hip_atomic_store(cnt + (size_t)(256 + bh * 16 + tid) * 32, tgt,
                                       __ATOMIC_RELAXED, __HIP_MEMORY_SCOPE_AGENT);
            } else {
                if (tid == 0) {
                    const unsigned* rl = cnt + (size_t)(256 + bh * 16 + (hg & 15)) * 32;
                    int spins = 0;
                    while (__hip_atomic_load(rl, __ATOMIC_RELAXED,
                                             __HIP_MEMORY_SCOPE_AGENT) < tgt
                           && spins < 8192) {
                        __builtin_amdgcn_s_sleep(1);
                        ++spins;
                    }
                }
                __syncthreads();   // WG released
            }

            // One inv per HD phases, right before the slot cycle wraps.
            if (((t + 1) & HMASK) == 0) {
                if (wave == 0)
                    asm volatile("buffer_inv sc0 sc1\n\ts_waitcnt vmcnt(0)" ::: "memory");
                __syncthreads();
            }
        }
    }
#undef MSTEP
#undef CSTEP
}

// ---------------------------------------------------------------------------
// Host side
// ---------------------------------------------------------------------------
extern "C" void kernel_launch(void* const* d_in, const int* in_sizes, int n_in,
                              void* d_out, int out_size, void* d_ws, size_t ws_size,
                              hipStream_t stream) {
    const float* x    = (const float*)d_in[0];
    const float* Wih0 = (const float*)d_in[1];
    const float* Whh0 = (const float*)d_in[2];
    const float* bih0 = (const float*)d_in[3];
    const float* bhh0 = (const float*)d_in[4];
    const float* Wih1 = (const float*)d_in[5];
    const float* Whh1 = (const float*)d_in[6];
    const float* bih1 = (const float*)d_in[7];
    const float* bhh1 = (const float*)d_in[8];
    float* out = (float*)d_out;
    (void)in_sizes; (void)n_in; (void)out_size; (void)ws_size;

    // Workspace carve (~65.1 MiB)
    uint8_t* w = (uint8_t*)d_ws;
    const size_t WMAT = (size_t)G4H * HH * 2;   // 8 MiB bf16 per matrix
    __hip_bfloat16* Wxs0 = (__hip_bfloat16*)(w);
    __hip_bfloat16* Whs0 = (__hip_bfloat16*)(w + WMAT);
    __hip_bfloat16* Wxs1 = (__hip_bfloat16*)(w + 2 * WMAT);
    __hip_bfloat16* Whs1 = (__hip_bfloat16*)(w + 3 * WMAT);
    size_t off = 4 * WMAT;
    __hip_bfloat16* xbuf = (__hip_bfloat16*)(w + off); off += (size_t)TT * BB * II * 2;
    __hip_bfloat16* h0seq = (__hip_bfloat16*)(w + off); off += (size_t)HD * BH * 2;
    __hip_bfloat16* h1seq = (__hip_bfloat16*)(w + off); off += (size_t)HD * BH * 2;
    unsigned* cnt = (unsigned*)(w + off); off += 65536;   // 16K words of lines

    init_bufs<<<256, 256, 0, stream>>>((unsigned*)h0seq, (unsigned*)h1seq, cnt);
    shuffle_w<<<(G4H * HH) / 256, 256, 0, stream>>>(Wih0, Wxs0);
    shuffle_w<<<(G4H * HH) / 256, 256, 0, stream>>>(Whh0, Whs0);
    shuffle_w<<<(G4H * HH) / 256, 256, 0, stream>>>(Wih1, Wxs1);
    shuffle_w<<<(G4H * HH) / 256, 256, 0, stream>>>(Whh1, Whs1);
    convert_x<<<(TT * BB * II) / 256, 256, 0, stream>>>(x, xbuf);

    lstm_persist<<<256, 512, 0, stream>>>(xbuf, Wxs0, Whs0, Wxs1, Whs1,
                                          bih0, bhh0, bih1, bhh1,
                                          h0seq, h1seq, out, cnt);
}